// Round 9
// baseline (228.661 us; speedup 1.0000x reference)
//
#include <hip/hip_runtime.h>
#include <math.h>

#define BN 16
#define DN 2048
#define ADA 1024
#define INTER 1024
#define NW2 32768   // D*RANK*2
#define HALFN 16384
#define KSL 16      // k2 k-slices

typedef __attribute__((address_space(1))) const void gv_t;
typedef __attribute__((address_space(3))) void lv_t;
__device__ __forceinline__ void gload_lds16(const float* g, float* l) {
    __builtin_amdgcn_global_load_lds((gv_t*)g, (lv_t*)l, 16, 0, 0);
}
#define WAITV(N) asm volatile("s_waitcnt vmcnt(" #N ")" ::: "memory")
#define WAITL0() asm volatile("s_waitcnt lgkmcnt(0)" ::: "memory")

// ===========================================================================
// K1a: p1[ks][m][j] = sum_{k in 32-chunk} ada[m][k]*w1[k][j]  (partial store,
// no atomics, no memset). grid (4 j-tiles, 32 ks), block 256.
__global__ void k1a(const float* __restrict__ ada, const float* __restrict__ w1,
                    float* __restrict__ p1) {
    const int j  = blockIdx.x * 256 + threadIdx.x;
    const int k0 = blockIdx.y * 32;
    __shared__ float al[32][16];
    for (int i = threadIdx.x; i < 512; i += 256)
        al[i >> 4][i & 15] = ada[(i & 15) * ADA + k0 + (i >> 4)];
    __syncthreads();
    float acc[BN];
#pragma unroll
    for (int m = 0; m < BN; ++m) acc[m] = 0.f;
    for (int kk = 0; kk < 32; ++kk) {
        float w = w1[(k0 + kk) * INTER + j];
#pragma unroll
        for (int m = 0; m < BN; ++m) acc[m] += al[kk][m] * w;
    }
    float* op = p1 + (size_t)blockIdx.y * (BN * INTER) + j;
#pragma unroll
    for (int m = 0; m < BN; ++m) op[m * INTER] = acc[m];
}

// ===========================================================================
// K1bt: h_t[k][m] = gelu_exact(b1[k] + sum_{ks<32} p1[ks][m][k])
__global__ void k1bt(const float* __restrict__ p1, const float* __restrict__ b1,
                     float* __restrict__ h_t) {
    int i = blockIdx.x * 256 + threadIdx.x;     // 16384, i = m*1024 + k
    int m = i >> 10, k = i & (INTER - 1);
    float v = b1[k];
#pragma unroll 8
    for (int ks = 0; ks < 32; ++ks) v += p1[ks * (BN * INTER) + i];
    float g = 0.5f * v * (1.f + erff(v * 0.70710678118654752f));
    h_t[k * BN + m] = g;
}

// ===========================================================================
// KBIG: fused role-split kernel.
//  blocks [0,512):  k2 role — p2[ks][m][n] = sum_{64k} h_t[k][m]*w2[k][n]
//    16 phases x 4 k-rows; 3 LDS buffers; global_load_lds staging with
//    COUNTED vmcnt waits (T4: never drain to 0 in-loop) + raw s_barrier.
//  blocks [512,768): k4 role — p4[cs][m][o] = sum_{32c} x[m][c]*base[c][o]
//    (r7-proven rolling-prefetch body; rides along for free overlap)
__global__ __launch_bounds__(256, 3) void kbig(const float* __restrict__ h_t,
                                               const float* __restrict__ w2,
                                               const float* __restrict__ x,
                                               const float* __restrict__ base,
                                               float* __restrict__ p2,
                                               float* __restrict__ p4) {
    __shared__ __align__(16) float smem[13312];   // 52 KB -> 3 blocks/CU
    const int tid = threadIdx.x;
    const int bx  = blockIdx.x;

    if (bx < 512) {
        // ------------------------- k2 role -------------------------------
        float* wl = smem;            // [3][4][1024] = 12288 floats
        float* hl = smem + 12288;    // [64][16]     = 1024 floats
        const int nt = bx & 31, ks = bx >> 5;
        const int n0 = nt * 1024, k0 = ks * 64;
        const int wv = tid >> 6, ln = tid & 63;

        // stage h (one-time): 1024 floats = 256 float4
        ((float4*)hl)[tid] = ((const float4*)(h_t + k0 * BN))[tid];

        float4 acc[BN];
#pragma unroll
        for (int m = 0; m < BN; ++m) acc[m] = make_float4(0.f, 0.f, 0.f, 0.f);

        // STAGE(b, ph): 4 rows x 4 KB; wave wv stages its 1 KB quarter/row.
        // dst = uniform base + lane*16 (hw); src per-lane ln*4 floats.
#define STAGE(b, ph) do {                                                     \
    const float* gs_ = w2 + (size_t)(k0 + (ph) * 4) * NW2 + n0                \
                     + wv * 256 + ln * 4;                                     \
    float* ls_ = wl + (b) * 4096 + wv * 256;                                  \
    gload_lds16(gs_ + (size_t)0 * NW2, ls_ + 0 * 1024);                       \
    gload_lds16(gs_ + (size_t)1 * NW2, ls_ + 1 * 1024);                       \
    gload_lds16(gs_ + (size_t)2 * NW2, ls_ + 2 * 1024);                       \
    gload_lds16(gs_ + (size_t)3 * NW2, ls_ + 3 * 1024);                       \
} while (0)
#define AC(m, hs) do { acc[m].x = fmaf(hs, wvv.x, acc[m].x);                  \
                       acc[m].y = fmaf(hs, wvv.y, acc[m].y);                  \
                       acc[m].z = fmaf(hs, wvv.z, acc[m].z);                  \
                       acc[m].w = fmaf(hs, wvv.w, acc[m].w); } while (0)
#define COMPUTE(b, ph) do {                                                   \
    _Pragma("unroll")                                                         \
    for (int i_ = 0; i_ < 4; ++i_) {                                          \
        const int kk_ = (ph) * 4 + i_;                                        \
        const float4 wvv = ((const float4*)(wl + (b) * 4096 + i_ * 1024))[tid];\
        const float4 h0 = ((const float4*)(hl + kk_ * 16))[0];                \
        const float4 h1 = ((const float4*)(hl + kk_ * 16))[1];                \
        const float4 h2 = ((const float4*)(hl + kk_ * 16))[2];                \
        const float4 h3 = ((const float4*)(hl + kk_ * 16))[3];                \
        AC(0,  h0.x); AC(1,  h0.y); AC(2,  h0.z); AC(3,  h0.w);               \
        AC(4,  h1.x); AC(5,  h1.y); AC(6,  h1.z); AC(7,  h1.w);               \
        AC(8,  h2.x); AC(9,  h2.y); AC(10, h2.z); AC(11, h2.w);               \
        AC(12, h3.x); AC(13, h3.y); AC(14, h3.z); AC(15, h3.w);               \
    }                                                                         \
} while (0)

        STAGE(0, 0);
        STAGE(1, 1);
        WAITL0();                        // own hl ds_write drained
        // 16 phases, fully unrolled so vmcnt literals are compile-time.
        // Per phase: counted wait (stage(ph) landed, stage(ph+1) flying) ->
        // barrier (all waves' data in LDS; prev compute done) ->
        // stage(ph+2) into the buffer freed last phase -> compute(ph).
#pragma unroll
        for (int ph = 0; ph < 16; ++ph) {
            if (ph < 15) { WAITV(4); } else { WAITV(0); }
            __builtin_amdgcn_s_barrier();
            __builtin_amdgcn_sched_barrier(0);
            if (ph < 14) {
                const int nb = (ph + 2) % 3;
                STAGE(nb, ph + 2);
            }
            const int cb = ph % 3;
            COMPUTE(cb, ph);
        }
#undef COMPUTE
#undef AC
#undef STAGE

        // write partial slice (coalesced float4 per m row)
        float* op = p2 + (size_t)ks * (BN * NW2) + n0 + tid * 4;
#pragma unroll
        for (int m = 0; m < BN; ++m)
            *(float4*)(op + (size_t)m * NW2) = acc[m];

    } else {
        // ------------------------- k4 role -------------------------------
        const int id2 = bx - 512;
        const int o4 = (id2 & 1) * 256 + tid;        // float4 col [0,512)
        const int c0 = ((id2 >> 1) & 63) * 32;
        const int m0 = (id2 >> 7) * 8;
        float* xl = smem;                             // [32][16]
        for (int i = tid; i < 512; i += 256)
            xl[i] = x[(i & 15) * DN + c0 + (i >> 4)];
        __syncthreads();

        float4 acc[8];
#pragma unroll
        for (int m = 0; m < 8; ++m) acc[m] = make_float4(0.f, 0.f, 0.f, 0.f);

        const float4* bp = (const float4*)base + (size_t)c0 * (DN / 4) + o4;
        float4 bbuf[8];
#pragma unroll
        for (int u = 0; u < 8; ++u) bbuf[u] = bp[(size_t)u * (DN / 4)];

        for (int cb = 0; cb < 32; cb += 8) {
#pragma unroll
            for (int u = 0; u < 8; ++u) {
                const int cc = cb + u;
                const float4 b = bbuf[u];
                const int cn = (cc + 8 < 32) ? (cc + 8) : cc;   // uniform clamp
                bbuf[u] = bp[(size_t)cn * (DN / 4)];
                const float4 x0 = *(const float4*)&xl[cc * 16 + 0];
                const float4 x1 = *(const float4*)&xl[cc * 16 + 4];
                const float4 x2 = *(const float4*)&xl[cc * 16 + 8];
                const float4 x3 = *(const float4*)&xl[cc * 16 + 12];
#define A4(mm, xs) do { acc[mm].x = fmaf(xs, b.x, acc[mm].x);                 \
                        acc[mm].y = fmaf(xs, b.y, acc[mm].y);                 \
                        acc[mm].z = fmaf(xs, b.z, acc[mm].z);                 \
                        acc[mm].w = fmaf(xs, b.w, acc[mm].w); } while (0)
                if (m0 == 0) {
                    A4(0, x0.x); A4(1, x0.y); A4(2, x0.z); A4(3, x0.w);
                    A4(4, x1.x); A4(5, x1.y); A4(6, x1.z); A4(7, x1.w);
                } else {
                    A4(0, x2.x); A4(1, x2.y); A4(2, x2.z); A4(3, x2.w);
                    A4(4, x3.x); A4(5, x3.y); A4(6, x3.z); A4(7, x3.w);
                }
#undef A4
            }
        }
        float4* op = (float4*)p4 + (size_t)((id2 >> 1) & 63) * (BN * DN / 4)
                   + (size_t)m0 * (DN / 4) + o4;
#pragma unroll
        for (int m = 0; m < 8; ++m) op[(size_t)m * (DN / 4)] = acc[m];
    }
}

// ===========================================================================
// K2r: xw[m][n] = b2[n] + sum_{ks<KSL} p2[ks][m][n]    (float4, coalesced)
__global__ void k2r(const float* __restrict__ p2, const float* __restrict__ b2,
                    float* __restrict__ xw) {
    const int i  = blockIdx.x * 256 + threadIdx.x;  // float4 idx over 131072
    const int n4 = i & (NW2 / 4 - 1);
    float4 s = ((const float4*)b2)[n4];
    const float4* p = (const float4*)p2 + i;
#pragma unroll
    for (int ks = 0; ks < KSL; ++ks) {
        float4 v = p[(size_t)ks * (BN * NW2 / 4)];
        s.x += v.x; s.y += v.y; s.z += v.z; s.w += v.w;
    }
    ((float4*)xw)[i] = s;
}

// ===========================================================================
// K3: t[m][r] = sum_c x[m][c] * xw[m][c*8+r]   (x_a half)
__global__ void k3(const float* __restrict__ x, const float* __restrict__ xw,
                   float* __restrict__ t) {
    const int m = blockIdx.x >> 3, r = blockIdx.x & 7;
    float s = 0.f;
    for (int c = threadIdx.x; c < DN; c += 256)
        s += x[m * DN + c] * xw[(size_t)m * NW2 + c * 8 + r];
    __shared__ float red[256];
    red[threadIdx.x] = s;
    __syncthreads();
    for (int off = 128; off > 0; off >>= 1) {
        if (threadIdx.x < off) red[threadIdx.x] += red[threadIdx.x + off];
        __syncthreads();
    }
    if (threadIdx.x == 0) t[m * 8 + r] = red[0];
}

// ===========================================================================
// K5: out[m][o] = x[m][o] + sum_{cs<64} p4[cs][m][o] + sum_r t[m][r]*x_b[m][o][r]
__global__ void k5(const float* __restrict__ x, const float* __restrict__ p4,
                   const float* __restrict__ xw, const float* __restrict__ t,
                   float* __restrict__ out) {
    const int i = blockIdx.x * 256 + threadIdx.x;   // [0, 32768)
    const int m = i >> 11, o = i & (DN - 1);
    float s = x[i];
    const float* p = p4 + i;
#pragma unroll 8
    for (int ks = 0; ks < 64; ++ks) s += p[ks * (BN * DN)];
    const float4 xb0 = *(const float4*)(xw + (size_t)m * NW2 + HALFN + o * 8);
    const float4 xb1 = *(const float4*)(xw + (size_t)m * NW2 + HALFN + o * 8 + 4);
    const float* tm = t + m * 8;
    s += tm[0] * xb0.x + tm[1] * xb0.y + tm[2] * xb0.z + tm[3] * xb0.w
       + tm[4] * xb1.x + tm[5] * xb1.y + tm[6] * xb1.z + tm[7] * xb1.w;
    out[i] = s;
}

// ===========================================================================
extern "C" void kernel_launch(void* const* d_in, const int* in_sizes, int n_in,
                              void* d_out, int out_size, void* d_ws, size_t ws_size,
                              hipStream_t stream) {
    const float* x    = (const float*)d_in[0];
    const float* ada  = (const float*)d_in[1];
    const float* base = (const float*)d_in[2];
    const float* w1   = (const float*)d_in[3];
    const float* b1   = (const float*)d_in[4];
    const float* w2   = (const float*)d_in[5];
    const float* b2   = (const float*)d_in[6];
    float* out = (float*)d_out;
    char* ws = (char*)d_ws;

    // ws layout (bytes):
    //   p2  @ 0           (16 * 16*32768*4 = 33,554,432)
    //   p4  @ 33,554,432  (64 * 16*2048*4 = 8,388,608)
    //   p1  @ 41,943,040  (32 * 16*1024*4 = 2,097,152)
    //   xw  @ 44,040,192  (2,097,152)
    //   h_t @ 46,137,344  (65,536)
    //   t   @ 46,202,880  (512)
    float* p2  = (float*)(ws);
    float* p4  = (float*)(ws + 33554432);
    float* p1  = (float*)(ws + 41943040);
    float* xw  = (float*)(ws + 44040192);
    float* h_t = (float*)(ws + 46137344);
    float* t   = (float*)(ws + 46202880);

    k1a <<<dim3(4, 32), 256, 0, stream>>>(ada, w1, p1);
    k1bt<<<64,          256, 0, stream>>>(p1, b1, h_t);
    kbig<<<768,         256, 0, stream>>>(h_t, w2, x, base, p2, p4);
    k2r <<<512,         256, 0, stream>>>(p2, b2, xw);
    k3  <<<128,         256, 0, stream>>>(x, xw, t);
    k5  <<<128,         256, 0, stream>>>(x, p4, xw, t, out);
}

// Round 10
// 72.539 us; speedup vs baseline: 3.1523x; 3.1523x over previous
//
#include <hip/hip_runtime.h>
#include <math.h>

#define BN 16
#define DN 2048
#define ADA 1024
#define INTER 1024
#define NW2 32768   // D*RANK*2
#define HALFN 16384
#define KSL 16      // k2 k-slices

typedef __attribute__((address_space(1))) const void gv_t;
typedef __attribute__((address_space(3))) void lv_t;
__device__ __forceinline__ void gload_lds16(const float* g, float* l) {
    __builtin_amdgcn_global_load_lds((gv_t*)g, (lv_t*)l, 16, 0, 0);
}
#define WAITV4() asm volatile("s_waitcnt vmcnt(4)" ::: "memory")
#define WAITV0() asm volatile("s_waitcnt vmcnt(0)" ::: "memory")
#define WAITL0() asm volatile("s_waitcnt lgkmcnt(0)" ::: "memory")

// ===========================================================================
// K1a: h_pre[m][j] += sum over k-chunk of ada[m][k]*w1[k][j]   (atomic k-split;
// 0.5M atomics total — measured tolerable in r1-r3)
__global__ void k1a(const float* __restrict__ ada, const float* __restrict__ w1,
                    float* __restrict__ h_pre) {
    const int j  = blockIdx.x * 256 + threadIdx.x;
    const int k0 = blockIdx.y * 32;
    __shared__ float a_lds[BN][32];
    for (int idx = threadIdx.x; idx < BN * 32; idx += 256) {
        int m = idx >> 5, kk = idx & 31;
        a_lds[m][kk] = ada[m * ADA + k0 + kk];
    }
    __syncthreads();
    float acc[BN];
#pragma unroll
    for (int m = 0; m < BN; ++m) acc[m] = 0.f;
    for (int kk = 0; kk < 32; ++kk) {
        float w = w1[(k0 + kk) * INTER + j];
#pragma unroll
        for (int m = 0; m < BN; ++m) acc[m] += a_lds[m][kk] * w;
    }
#pragma unroll
    for (int m = 0; m < BN; ++m) atomicAdd(&h_pre[m * INTER + j], acc[m]);
}

// ===========================================================================
// K1b-T: h_t[k][m] = gelu_exact(h_pre[m][k] + b1[k])   (transposed output)
__global__ void k1bt(const float* __restrict__ h_pre, const float* __restrict__ b1,
                     float* __restrict__ h_t) {
    int i = blockIdx.x * 256 + threadIdx.x;     // 16384 elements
    int m = i >> 10, j = i & (INTER - 1);
    float v = h_pre[i] + b1[j];
    float g = 0.5f * v * (1.f + erff(v * 0.70710678118654752f));
    h_t[j * BN + m] = g;
}

// ===========================================================================
// K2p: p2[ks][m][n] = sum_{k in 64-chunk} h_t[k][m] * w2[k][n]
// grid (32 n-tiles, 16 k-slices) = 512 blocks, 256 thr (4 waves), 52 KB LDS
// -> 3 blocks/CU capacity, all 512 co-resident (2/CU).
// T4 pipeline: 3 LDS buffers, global_load_lds staging, COUNTED vmcnt(4)
// (vmcnt(0) only at tail), raw s_barrier, ROLLED loop (no unroll, no
// sched_barrier, no launch-bounds VGPR cap — r9's spill causes removed).
__global__ __launch_bounds__(256) void k2p(const float* __restrict__ h_t,
                                           const float* __restrict__ w2,
                                           float* __restrict__ p2) {
    const int tid = threadIdx.x;
    const int wv  = tid >> 6, ln = tid & 63;
    const int n0  = blockIdx.x * 1024;          // n window (floats)
    const int k0  = blockIdx.y * 64;            // k range
    __shared__ __align__(16) float wl[3][4][1024];   // 48 KB, 3 buffers
    __shared__ __align__(16) float hl[64][16];       // 4 KB h stage

    // one-time h stage: 1024 floats = 256 float4 (one per thread)
    ((float4*)hl)[tid] = ((const float4*)(h_t + k0 * BN))[tid];
    WAITL0();                                   // ds_write drained pre-barrier

    float4 acc[BN];
#pragma unroll
    for (int m = 0; m < BN; ++m) acc[m] = make_float4(0.f, 0.f, 0.f, 0.f);

    // STAGE(b, ph): 4 k-rows x 4 KB; wave wv stages its 1 KB quarter of each
    // row. LDS dst = uniform base + lane*16 (hw rule); only vmem in the loop.
#define STAGE(b, ph) do {                                                     \
    const float* gs_ = w2 + (size_t)(k0 + (ph) * 4) * NW2 + n0                \
                     + wv * 256 + ln * 4;                                     \
    float* ls_ = &wl[b][0][wv * 256];                                         \
    gload_lds16(gs_ + (size_t)0 * NW2, ls_ + 0 * 1024);                       \
    gload_lds16(gs_ + (size_t)1 * NW2, ls_ + 1 * 1024);                       \
    gload_lds16(gs_ + (size_t)2 * NW2, ls_ + 2 * 1024);                       \
    gload_lds16(gs_ + (size_t)3 * NW2, ls_ + 3 * 1024);                       \
} while (0)
#define AC(m, hs) do { acc[m].x = fmaf(hs, wvv.x, acc[m].x);                  \
                       acc[m].y = fmaf(hs, wvv.y, acc[m].y);                  \
                       acc[m].z = fmaf(hs, wvv.z, acc[m].z);                  \
                       acc[m].w = fmaf(hs, wvv.w, acc[m].w); } while (0)
#define COMPUTE(b, ph) do {                                                   \
    _Pragma("unroll")                                                         \
    for (int i_ = 0; i_ < 4; ++i_) {                                          \
        const int kk_ = (ph) * 4 + i_;                                        \
        const float4 wvv = ((const float4*)&wl[b][i_][0])[tid];               \
        const float4 h0 = ((const float4*)&hl[kk_][0])[0];                    \
        const float4 h1 = ((const float4*)&hl[kk_][0])[1];                    \
        const float4 h2 = ((const float4*)&hl[kk_][0])[2];                    \
        const float4 h3 = ((const float4*)&hl[kk_][0])[3];                    \
        AC(0,  h0.x); AC(1,  h0.y); AC(2,  h0.z); AC(3,  h0.w);               \
        AC(4,  h1.x); AC(5,  h1.y); AC(6,  h1.z); AC(7,  h1.w);               \
        AC(8,  h2.x); AC(9,  h2.y); AC(10, h2.z); AC(11, h2.w);               \
        AC(12, h3.x); AC(13, h3.y); AC(14, h3.z); AC(15, h3.w);               \
    }                                                                         \
} while (0)

    STAGE(0, 0);
    STAGE(1, 1);
    // steady state: at iter ph, in flight = stage(ph) + stage(ph+1) = 8.
    // WAITV4 -> stage(ph) landed, stage(ph+1) still flying across the barrier.
    // stage(ph+2) overwrites the buffer compute(ph-1) finished (all waves
    // passed this barrier after computing ph-1) — race-free, distinct mod 3.
    int cb = 0, nb = 2;
    for (int ph = 0; ph < 15; ++ph) {
        WAITV4();
        __builtin_amdgcn_s_barrier();
        if (ph < 14) STAGE(nb, ph + 2);
        COMPUTE(cb, ph);
        cb = (cb == 2) ? 0 : cb + 1;
        nb = (nb == 2) ? 0 : nb + 1;
    }
    WAITV0();                          // tail: stage(15) fully landed
    __builtin_amdgcn_s_barrier();
    COMPUTE(cb, 15);
#undef COMPUTE
#undef AC
#undef STAGE

    // partial-slice write (coalesced float4 per m row)
    float* op = p2 + (size_t)blockIdx.y * (BN * NW2) + n0 + tid * 4;
#pragma unroll
    for (int m = 0; m < BN; ++m)
        *(float4*)(op + (size_t)m * NW2) = acc[m];
}

// ===========================================================================
// K2r: xw[m][n] = b2[n] + sum_{ks<KSL} p2[ks][m][n]    (float4, coalesced)
__global__ void k2r(const float* __restrict__ p2, const float* __restrict__ b2,
                    float* __restrict__ xw) {
    const int i  = blockIdx.x * 256 + threadIdx.x;  // float4 idx over 131072
    const int n4 = i & (NW2 / 4 - 1);
    float4 s = ((const float4*)b2)[n4];
    const float4* p = (const float4*)p2 + i;
#pragma unroll
    for (int ks = 0; ks < KSL; ++ks) {
        float4 v = p[(size_t)ks * (BN * NW2 / 4)];
        s.x += v.x; s.y += v.y; s.z += v.z; s.w += v.w;
    }
    ((float4*)xw)[i] = s;
}

// ===========================================================================
// K3: t[m][r] = sum_c x[m][c] * xw[m][c*8+r]   (x_a half)
__global__ void k3(const float* __restrict__ x, const float* __restrict__ xw,
                   float* __restrict__ t) {
    const int m = blockIdx.x >> 3, r = blockIdx.x & 7;
    float s = 0.f;
    for (int c = threadIdx.x; c < DN; c += 256)
        s += x[m * DN + c] * xw[(size_t)m * NW2 + c * 8 + r];
    __shared__ float red[256];
    red[threadIdx.x] = s;
    __syncthreads();
    for (int off = 128; off > 0; off >>= 1) {
        if (threadIdx.x < off) red[threadIdx.x] += red[threadIdx.x + off];
        __syncthreads();
    }
    if (threadIdx.x == 0) t[m * 8 + r] = red[0];
}

// ===========================================================================
// K4m: p4[cs][m][o] = sum_{c in 32-chunk} x[m][c] * base[c][o]
// grid (2, 64, 2), block 256. Thread owns float4 of o for 8 m; no LDS.
#define K4ACC(i, xv) do { acc[i].x = fmaf((xv), b.x, acc[i].x); \
                          acc[i].y = fmaf((xv), b.y, acc[i].y); \
                          acc[i].z = fmaf((xv), b.z, acc[i].z); \
                          acc[i].w = fmaf((xv), b.w, acc[i].w); } while (0)
__global__ __launch_bounds__(256) void k4m(const float* __restrict__ x,
                                           const float* __restrict__ base,
                                           float* __restrict__ p4) {
    const int o4 = blockIdx.x * 256 + threadIdx.x;   // [0, 512)
    const int c0 = blockIdx.y * 32;
    const int m0 = blockIdx.z * 8;
    float4 acc[8];
#pragma unroll
    for (int m = 0; m < 8; ++m) acc[m] = make_float4(0.f, 0.f, 0.f, 0.f);

    const float4* bp = (const float4*)base + (size_t)c0 * (DN / 4) + o4;
    float4 bbuf[8];
#pragma unroll
    for (int u = 0; u < 8; ++u) bbuf[u] = bp[(size_t)u * (DN / 4)];

    for (int cb = 0; cb < 32; cb += 8) {
#pragma unroll
        for (int u = 0; u < 8; ++u) {
            const int cc = cb + u;
            const float4 b = bbuf[u];
            const int cn = (cc + 8 < 32) ? (cc + 8) : cc;    // uniform clamp
            bbuf[u] = bp[(size_t)cn * (DN / 4)];
            const float x0 = x[(m0 + 0) * DN + c0 + cc];
            const float x1 = x[(m0 + 1) * DN + c0 + cc];
            const float x2 = x[(m0 + 2) * DN + c0 + cc];
            const float x3 = x[(m0 + 3) * DN + c0 + cc];
            const float x4 = x[(m0 + 4) * DN + c0 + cc];
            const float x5 = x[(m0 + 5) * DN + c0 + cc];
            const float x6 = x[(m0 + 6) * DN + c0 + cc];
            const float x7 = x[(m0 + 7) * DN + c0 + cc];
            K4ACC(0, x0); K4ACC(1, x1); K4ACC(2, x2); K4ACC(3, x3);
            K4ACC(4, x4); K4ACC(5, x5); K4ACC(6, x6); K4ACC(7, x7);
        }
    }
    float4* op = (float4*)p4 + (size_t)blockIdx.y * (BN * DN / 4)
               + (size_t)m0 * (DN / 4) + o4;
#pragma unroll
    for (int m = 0; m < 8; ++m) op[(size_t)m * (DN / 4)] = acc[m];
}

// ===========================================================================
// K5: out[m][o] = x[m][o] + sum_{cs<64} p4[cs][m][o] + sum_r t[m][r]*x_b[m][o][r]
__global__ void k5(const float* __restrict__ x, const float* __restrict__ p4,
                   const float* __restrict__ xw, const float* __restrict__ t,
                   float* __restrict__ out) {
    const int i = blockIdx.x * 256 + threadIdx.x;   // [0, 32768)
    const int m = i >> 11, o = i & (DN - 1);
    float s = x[i];
    const float* p = p4 + i;
#pragma unroll 8
    for (int ks = 0; ks < 64; ++ks) s += p[ks * (BN * DN)];
    const float4 xb0 = *(const float4*)(xw + (size_t)m * NW2 + HALFN + o * 8);
    const float4 xb1 = *(const float4*)(xw + (size_t)m * NW2 + HALFN + o * 8 + 4);
    const float* tm = t + m * 8;
    s += tm[0] * xb0.x + tm[1] * xb0.y + tm[2] * xb0.z + tm[3] * xb0.w
       + tm[4] * xb1.x + tm[5] * xb1.y + tm[6] * xb1.z + tm[7] * xb1.w;
    out[i] = s;
}

// ===========================================================================
extern "C" void kernel_launch(void* const* d_in, const int* in_sizes, int n_in,
                              void* d_out, int out_size, void* d_ws, size_t ws_size,
                              hipStream_t stream) {
    const float* x    = (const float*)d_in[0];
    const float* ada  = (const float*)d_in[1];
    const float* base = (const float*)d_in[2];
    const float* w1   = (const float*)d_in[3];
    const float* b1   = (const float*)d_in[4];
    const float* w2   = (const float*)d_in[5];
    const float* b2   = (const float*)d_in[6];
    float* out = (float*)d_out;
    char* ws = (char*)d_ws;

    // ws layout (bytes):
    //   p2    @ 0           (16 * 16*32768*4 = 33,554,432)
    //   xw    @ 33,554,432  (2,097,152)
    //   p4    @ 35,651,584  (64 * 16*2048*4 = 8,388,608)
    //   h_pre @ 44,040,192  (65,536)
    //   h_t   @ 44,105,728  (65,536)
    //   t     @ 44,171,264  (512)
    float* p2    = (float*)(ws);
    float* xw    = (float*)(ws + 33554432);
    float* p4    = (float*)(ws + 35651584);
    float* h_pre = (float*)(ws + 44040192);
    float* h_t   = (float*)(ws + 44105728);
    float* t     = (float*)(ws + 44171264);

    hipMemsetAsync(h_pre, 0, 65536, stream);   // k1a atomic accumulator only

    k1a <<<dim3(4, 32),    256, 0, stream>>>(ada, w1, h_pre);
    k1bt<<<64,             256, 0, stream>>>(h_pre, b1, h_t);
    k2p <<<dim3(32, KSL),  256, 0, stream>>>(h_t, w2, p2);
    k4m <<<dim3(2, 64, 2), 256, 0, stream>>>(x, base, p4);
    k2r <<<512,            256, 0, stream>>>(p2, b2, xw);
    k3  <<<128,            256, 0, stream>>>(x, xw, t);
    k5  <<<128,            256, 0, stream>>>(x, p4, xw, t, out);
}